// Round 1
// baseline (59.482 us; speedup 1.0000x reference)
//
#include <hip/hip_runtime.h>
#include <math.h>

#define IMG 256
#define NFACE 1000
#define NCHUNK 8
#define FPC (NFACE / NCHUNK)   // 125 faces per chunk
#define EPSF 1e-8f

// Static device scratch (graph-capture safe, no ws_size assumptions).
__device__ float g_coeff[NFACE * 12];            // per face: 3 edges x (cx, cy, c0, pad)
__device__ float g_partial[NCHUNK * IMG * IMG];  // partial log-sums per chunk per pixel

// ---------------------------------------------------------------------------
// Kernel 1: per-face edge coefficients.
// ---------------------------------------------------------------------------
__global__ __launch_bounds__(256) void k_coeff(const float* __restrict__ verts,
                                               const int* __restrict__ faces,
                                               const float* __restrict__ q,
                                               const float* __restrict__ t,
                                               const float* __restrict__ K) {
    int f = blockIdx.x * blockDim.x + threadIdx.x;
    if (f >= NFACE) return;

    // Quaternion -> rotation (redundant per thread; trivially cheap).
    float qw = q[0], qx = q[1], qy = q[2], qz = q[3];
    float qn = sqrtf(qw * qw + qx * qx + qy * qy + qz * qz + EPSF);
    qw /= qn; qx /= qn; qy /= qn; qz /= qn;
    float R00 = 1.f - 2.f * (qy * qy + qz * qz);
    float R01 = 2.f * (qx * qy - qw * qz);
    float R02 = 2.f * (qx * qz + qw * qy);
    float R10 = 2.f * (qx * qy + qw * qz);
    float R11 = 1.f - 2.f * (qx * qx + qz * qz);
    float R12 = 2.f * (qy * qz - qw * qx);
    float R20 = 2.f * (qx * qz - qw * qy);
    float R21 = 2.f * (qy * qz + qw * qx);
    float R22 = 1.f - 2.f * (qx * qx + qy * qy);
    float tx = t[0], ty = t[1], tz = t[2];
    float K00 = K[0], K02 = K[2], K11 = K[4], K12 = K[5];

    float X[3], Y[3];
#pragma unroll
    for (int k = 0; k < 3; ++k) {
        int vi = faces[f * 3 + k];
        float vx = verts[vi * 3 + 0];
        float vy = verts[vi * 3 + 1];
        float vz = verts[vi * 3 + 2];
        float cx = R00 * vx + R01 * vy + R02 * vz + tx;
        float cy = R10 * vx + R11 * vy + R12 * vz + ty;
        float cz = R20 * vx + R21 * vy + R22 * vz + tz;
        float z = cz + EPSF;
        X[k] = K00 * cx / z + K02;
        Y[k] = K11 * cy / z + K12;
    }

    float e01x = X[1] - X[0], e01y = Y[1] - Y[0];
    float e02x = X[2] - X[0], e02y = Y[2] - Y[0];
    float area2 = e01x * e02y - e01y * e02x;
    float s = (area2 >= 0.f) ? 1.f : -1.f;

    float4* dst = reinterpret_cast<float4*>(&g_coeff[f * 12]);
#pragma unroll
    for (int k = 0; k < 3; ++k) {
        int k1 = (k + 1) % 3;  // unrolled -> compile-time
        float ex = X[k1] - X[k];
        float ey = Y[k1] - Y[k];
        float inv_len = s / sqrtf(ex * ex + ey * ey + EPSF);
        float cx = -ey * inv_len;
        float cy = ex * inv_len;
        float c0 = (ey * X[k] - ex * Y[k]) * inv_len;
        dst[k] = make_float4(cx, cy, c0, 0.f);
    }
}

// ---------------------------------------------------------------------------
// Kernel 2: heavy pass. blockIdx.x = face chunk, blockIdx.y = image row.
// Each thread owns one pixel (col = tid), loops over 125 faces with
// wave-uniform coefficient reads (expect s_load scalarization).
// ---------------------------------------------------------------------------
__global__ __launch_bounds__(256) void k_partial() {
    const int chunk = blockIdx.x;
    const int row = blockIdx.y;
    const int col = threadIdx.x;
    const float px = col + 0.5f;
    const float py = row + 0.5f;

    const float4* __restrict__ cf =
        reinterpret_cast<const float4*>(&g_coeff[chunk * FPC * 12]);

    float acc = 0.f;
#pragma unroll 5
    for (int f = 0; f < FPC; ++f) {
        float4 a = cf[f * 3 + 0];
        float4 b = cf[f * 3 + 1];
        float4 c = cf[f * 3 + 2];
        float c0 = fmaf(px, a.x, fmaf(py, a.y, a.z));
        float c1 = fmaf(px, b.x, fmaf(py, b.y, b.z));
        float c2 = fmaf(px, c.x, fmaf(py, c.y, c.z));
        float d = fminf(fminf(c0, c1), c2);
        // log_sigmoid(-d) = -softplus(d) = -(max(d,0) + log(1+exp(-|d|)))
        float e = __expf(-fabsf(d));
        acc -= fmaxf(d, 0.f) + __logf(1.f + e);
    }
    g_partial[chunk * (IMG * IMG) + row * IMG + col] = acc;
}

// ---------------------------------------------------------------------------
// Kernel 3: combine chunks, silhouette, squared error, row-mean reduce.
// One block per row.
// ---------------------------------------------------------------------------
__global__ __launch_bounds__(256) void k_final(const float* __restrict__ image_ref,
                                               float* __restrict__ out) {
    const int row = blockIdx.x;
    const int col = threadIdx.x;
    const int pix = row * IMG + col;

    float ssum = 0.f;
#pragma unroll
    for (int c = 0; c < NCHUNK; ++c) ssum += g_partial[c * (IMG * IMG) + pix];

    float sil = 1.f - __expf(ssum);
    float diff = sil - image_ref[pix];
    float v = diff * diff;

    // wave (64-lane) reduce
#pragma unroll
    for (int o = 32; o > 0; o >>= 1) v += __shfl_down(v, o);

    __shared__ float wsum[4];
    if ((col & 63) == 0) wsum[col >> 6] = v;
    __syncthreads();
    if (col == 0) {
        out[row] = (wsum[0] + wsum[1] + wsum[2] + wsum[3]) * (1.f / 256.f);
    }
}

// ---------------------------------------------------------------------------
extern "C" void kernel_launch(void* const* d_in, const int* in_sizes, int n_in,
                              void* d_out, int out_size, void* d_ws, size_t ws_size,
                              hipStream_t stream) {
    const float* verts = (const float*)d_in[0];   // (1,1000,3) f32
    const int* faces = (const int*)d_in[1];       // (1,1000,3) i32
    const float* q = (const float*)d_in[2];       // (4,) f32
    const float* t = (const float*)d_in[3];       // (3,) f32
    const float* K = (const float*)d_in[4];       // (3,3) f32
    const float* image_ref = (const float*)d_in[5];  // (256,256) f32
    float* out = (float*)d_out;                   // (256,) f32

    k_coeff<<<(NFACE + 255) / 256, 256, 0, stream>>>(verts, faces, q, t, K);
    k_partial<<<dim3(NCHUNK, IMG), 256, 0, stream>>>();
    k_final<<<IMG, 256, 0, stream>>>(image_ref, out);
}

// Round 2
// 58.624 us; speedup vs baseline: 1.0146x; 1.0146x over previous
//
#include <hip/hip_runtime.h>
#include <math.h>

#define IMG 256
#define NFACE 1000
#define NCHUNK 8
#define FPC (NFACE / NCHUNK)   // 125 faces per chunk
#define EPSF 1e-8f
#define LOG2E 1.44269504088896f

// Static device scratch (graph-capture safe, no ws_size assumptions).
__device__ float g_coeff[NFACE * 12];            // per face: 3 edges x (cx, cy, c0, pad), pre-scaled by log2(e)
__device__ float g_partial[NCHUNK * IMG * IMG];  // partial log2-sums per chunk per pixel

// ---------------------------------------------------------------------------
// Kernel 1: per-face edge coefficients, pre-scaled by log2(e) so the heavy
// pass works natively in log2 space (raw v_exp_f32 / v_log_f32, no scaling).
// ---------------------------------------------------------------------------
__global__ __launch_bounds__(256) void k_coeff(const float* __restrict__ verts,
                                               const int* __restrict__ faces,
                                               const float* __restrict__ q,
                                               const float* __restrict__ t,
                                               const float* __restrict__ K) {
    int f = blockIdx.x * blockDim.x + threadIdx.x;
    if (f >= NFACE) return;

    float qw = q[0], qx = q[1], qy = q[2], qz = q[3];
    float qn = sqrtf(qw * qw + qx * qx + qy * qy + qz * qz + EPSF);
    qw /= qn; qx /= qn; qy /= qn; qz /= qn;
    float R00 = 1.f - 2.f * (qy * qy + qz * qz);
    float R01 = 2.f * (qx * qy - qw * qz);
    float R02 = 2.f * (qx * qz + qw * qy);
    float R10 = 2.f * (qx * qy + qw * qz);
    float R11 = 1.f - 2.f * (qx * qx + qz * qz);
    float R12 = 2.f * (qy * qz - qw * qx);
    float R20 = 2.f * (qx * qz - qw * qy);
    float R21 = 2.f * (qy * qz + qw * qx);
    float R22 = 1.f - 2.f * (qx * qx + qy * qy);
    float tx = t[0], ty = t[1], tz = t[2];
    float K00 = K[0], K02 = K[2], K11 = K[4], K12 = K[5];

    float X[3], Y[3];
#pragma unroll
    for (int k = 0; k < 3; ++k) {
        int vi = faces[f * 3 + k];
        float vx = verts[vi * 3 + 0];
        float vy = verts[vi * 3 + 1];
        float vz = verts[vi * 3 + 2];
        float cx = R00 * vx + R01 * vy + R02 * vz + tx;
        float cy = R10 * vx + R11 * vy + R12 * vz + ty;
        float cz = R20 * vx + R21 * vy + R22 * vz + tz;
        float z = cz + EPSF;
        X[k] = K00 * cx / z + K02;
        Y[k] = K11 * cy / z + K12;
    }

    float e01x = X[1] - X[0], e01y = Y[1] - Y[0];
    float e02x = X[2] - X[0], e02y = Y[2] - Y[0];
    float area2 = e01x * e02y - e01y * e02x;
    float s = (area2 >= 0.f) ? LOG2E : -LOG2E;   // fold log2(e) into all coeffs

    float4* dst = reinterpret_cast<float4*>(&g_coeff[f * 12]);
#pragma unroll
    for (int k = 0; k < 3; ++k) {
        int k1 = (k + 1) % 3;  // unrolled -> compile-time
        float ex = X[k1] - X[k];
        float ey = Y[k1] - Y[k];
        float inv_len = s / sqrtf(ex * ex + ey * ey + EPSF);
        float cx = -ey * inv_len;
        float cy = ex * inv_len;
        float c0 = (ey * X[k] - ex * Y[k]) * inv_len;
        dst[k] = make_float4(cx, cy, c0, 0.f);
    }
}

// ---------------------------------------------------------------------------
// Kernel 2: heavy pass. blockIdx.x = face chunk, blockIdx.y = image row.
// One thread per pixel. Works in log2 space:
//   softplus_log2(u) = max(u,0) + log2(1 + 2^-|u|)
// The correction term is < 2^-20 when |u| >= 20 (|d| >= ~13.9 px) -> branch
// around both transcendentals; s_cbranch_execz skips the block entirely for
// the ~85% of waves with no lane near a triangle edge.
// ---------------------------------------------------------------------------
__global__ __launch_bounds__(256) void k_partial() {
    const int chunk = blockIdx.x;
    const int row = blockIdx.y;
    const int col = threadIdx.x;
    const float px = col + 0.5f;
    const float py = row + 0.5f;

    const float4* __restrict__ cf =
        reinterpret_cast<const float4*>(&g_coeff[chunk * FPC * 12]);

    float acc = 0.f;  // accumulates softplus_log2 >= 0
#pragma unroll 5
    for (int f = 0; f < FPC; ++f) {
        float4 a = cf[f * 3 + 0];
        float4 b = cf[f * 3 + 1];
        float4 c = cf[f * 3 + 2];
        float c0 = fmaf(px, a.x, fmaf(py, a.y, a.z));
        float c1 = fmaf(px, b.x, fmaf(py, b.y, b.z));
        float c2 = fmaf(px, c.x, fmaf(py, c.y, c.z));
        float u = fminf(fminf(c0, c1), c2);   // v_min3_f32
        acc += fmaxf(u, 0.f);
        float au = fabsf(u);
        if (au < 20.f) {
            acc += log2f(1.f + exp2f(-au));   // raw v_exp_f32 + v_log_f32
        }
    }
    g_partial[chunk * (IMG * IMG) + row * IMG + col] = acc;
}

// ---------------------------------------------------------------------------
// Kernel 3: combine chunks, silhouette, squared error, row-mean reduce.
// sil = 1 - exp(sum log_sigmoid) = 1 - 2^(-acc_total)
// ---------------------------------------------------------------------------
__global__ __launch_bounds__(256) void k_final(const float* __restrict__ image_ref,
                                               float* __restrict__ out) {
    const int row = blockIdx.x;
    const int col = threadIdx.x;
    const int pix = row * IMG + col;

    float ssum = 0.f;
#pragma unroll
    for (int c = 0; c < NCHUNK; ++c) ssum += g_partial[c * (IMG * IMG) + pix];

    float sil = 1.f - exp2f(-ssum);
    float diff = sil - image_ref[pix];
    float v = diff * diff;

#pragma unroll
    for (int o = 32; o > 0; o >>= 1) v += __shfl_down(v, o);

    __shared__ float wsum[4];
    if ((col & 63) == 0) wsum[col >> 6] = v;
    __syncthreads();
    if (col == 0) {
        out[row] = (wsum[0] + wsum[1] + wsum[2] + wsum[3]) * (1.f / 256.f);
    }
}

// ---------------------------------------------------------------------------
extern "C" void kernel_launch(void* const* d_in, const int* in_sizes, int n_in,
                              void* d_out, int out_size, void* d_ws, size_t ws_size,
                              hipStream_t stream) {
    const float* verts = (const float*)d_in[0];   // (1,1000,3) f32
    const int* faces = (const int*)d_in[1];       // (1,1000,3) i32
    const float* q = (const float*)d_in[2];       // (4,) f32
    const float* t = (const float*)d_in[3];       // (3,) f32
    const float* K = (const float*)d_in[4];       // (3,3) f32
    const float* image_ref = (const float*)d_in[5];  // (256,256) f32
    float* out = (float*)d_out;                   // (256,) f32

    k_coeff<<<(NFACE + 255) / 256, 256, 0, stream>>>(verts, faces, q, t, K);
    k_partial<<<dim3(NCHUNK, IMG), 256, 0, stream>>>();
    k_final<<<IMG, 256, 0, stream>>>(image_ref, out);
}

// Round 4
// 46.244 us; speedup vs baseline: 1.2863x; 1.2677x over previous
//
#include <hip/hip_runtime.h>
#include <math.h>

#define IMG 256
#define NFACE 1000
#define NCHUNK 20
#define FPC (NFACE / NCHUNK)   // 50 faces per chunk
#define EPSF 1e-8f
#define LOG2E 1.44269504088896f
#define TCUT 16.0f             // drop softplus correction beyond |u| >= 16
#define TBAND 11.1f            // TCUT / log2(e), pixel-space band half-width

struct __align__(16) FaceRec {
    int4 bb;            // xmin, ymin, xmax, ymax (pixel-index space, conservative)
    float4 e0, e1, e2;  // per edge: (cx, cy, c0, pad), pre-scaled by log2(e)
};

// Static device scratch (graph-capture safe).
__device__ FaceRec g_face[NFACE];
__device__ float g_partial[NCHUNK * IMG * IMG];

// ---------------------------------------------------------------------------
// Kernel 1: per-face edge coefficients + conservative integer bbox of the
// region {d >= -TBAND}. For a nondegenerate triangle that region is exactly
// the triangle with vertices P_k = V_k - t*(n_i + n_j)/(1 + n_i.n_j).
// DEGENERATE faces (repeated vertex index -> zero-length projected edge ->
// that edge's constraint is c==0 over the whole plane, and the face paints an
// infinite line band) get a full-image bbox: never culled, always exact.
// ---------------------------------------------------------------------------
__global__ __launch_bounds__(256) void k_coeff(const float* __restrict__ verts,
                                               const int* __restrict__ faces,
                                               const float* __restrict__ q,
                                               const float* __restrict__ t,
                                               const float* __restrict__ K) {
    int f = blockIdx.x * blockDim.x + threadIdx.x;
    if (f >= NFACE) return;

    float qw = q[0], qx = q[1], qy = q[2], qz = q[3];
    float qn = sqrtf(qw * qw + qx * qx + qy * qy + qz * qz + EPSF);
    qw /= qn; qx /= qn; qy /= qn; qz /= qn;
    float R00 = 1.f - 2.f * (qy * qy + qz * qz);
    float R01 = 2.f * (qx * qy - qw * qz);
    float R02 = 2.f * (qx * qz + qw * qy);
    float R10 = 2.f * (qx * qy + qw * qz);
    float R11 = 1.f - 2.f * (qx * qx + qz * qz);
    float R12 = 2.f * (qy * qz - qw * qx);
    float R20 = 2.f * (qx * qz - qw * qy);
    float R21 = 2.f * (qy * qz + qw * qx);
    float R22 = 1.f - 2.f * (qx * qx + qy * qy);
    float tx = t[0], ty = t[1], tz = t[2];
    float K00 = K[0], K02 = K[2], K11 = K[4], K12 = K[5];

    float X[3], Y[3];
#pragma unroll
    for (int k = 0; k < 3; ++k) {
        int vi = faces[f * 3 + k];
        float vx = verts[vi * 3 + 0];
        float vy = verts[vi * 3 + 1];
        float vz = verts[vi * 3 + 2];
        float cx = R00 * vx + R01 * vy + R02 * vz + tx;
        float cy = R10 * vx + R11 * vy + R12 * vz + ty;
        float cz = R20 * vx + R21 * vy + R22 * vz + tz;
        float z = cz + EPSF;
        X[k] = K00 * cx / z + K02;
        Y[k] = K11 * cy / z + K12;
    }

    float e01x = X[1] - X[0], e01y = Y[1] - Y[0];
    float e02x = X[2] - X[0], e02y = Y[2] - Y[0];
    float area2 = e01x * e02y - e01y * e02x;
    float s = (area2 >= 0.f) ? 1.f : -1.f;

    float ucx[3], ucy[3], uc0[3];  // ~unit inward normals + offset (unscaled)
    bool degen = false;
#pragma unroll
    for (int k = 0; k < 3; ++k) {
        int k1 = (k + 1) % 3;
        float ex = X[k1] - X[k];
        float ey = Y[k1] - Y[k];
        float l2 = ex * ex + ey * ey;
        degen = degen || (l2 < 1e-6f);   // zero-length edge: c==0 everywhere
        float inv = s / sqrtf(l2 + EPSF);
        ucx[k] = -ey * inv;
        ucy[k] = ex * inv;
        uc0[k] = (ey * X[k] - ex * Y[k]) * inv;
    }

    int4 bbi;
    if (degen) {
        bbi = make_int4(0, 0, IMG - 1, IMG - 1);  // never cull
    } else {
        // bbox of the three shifted-line intersection points P_k.
        float xmn = 1e9f, xmx = -1e9f, ymn = 1e9f, ymx = -1e9f;
#pragma unroll
        for (int k = 0; k < 3; ++k) {
            int i = (k + 2) % 3, j = k;  // the two edges meeting at vertex k
            float dt = ucx[i] * ucx[j] + ucy[i] * ucy[j];
            float w = TBAND / fmaxf(1.f + dt, 1e-4f);
            float Px = X[k] - (ucx[i] + ucx[j]) * w;
            float Py = Y[k] - (ucy[i] + ucy[j]) * w;
            Px = fminf(fmaxf(Px, -2e4f), 2e4f);
            Py = fminf(fmaxf(Py, -2e4f), 2e4f);
            xmn = fminf(xmn, Px); xmx = fmaxf(xmx, Px);
            ymn = fminf(ymn, Py); ymx = fmaxf(ymx, Py);
        }
        bbi = make_int4((int)floorf(xmn) - 1, (int)floorf(ymn) - 1,
                        (int)ceilf(xmx) + 1, (int)ceilf(ymx) + 1);
    }

    FaceRec r;
    r.bb = bbi;
    r.e0 = make_float4(ucx[0] * LOG2E, ucy[0] * LOG2E, uc0[0] * LOG2E, 0.f);
    r.e1 = make_float4(ucx[1] * LOG2E, ucy[1] * LOG2E, uc0[1] * LOG2E, 0.f);
    r.e2 = make_float4(ucx[2] * LOG2E, ucy[2] * LOG2E, uc0[2] * LOG2E, 0.f);
    g_face[f] = r;
}

// ---------------------------------------------------------------------------
// Kernel 2: heavy pass with wave-level bbox culling.
// blockIdx.x = face chunk (20), blockIdx.y = row. Wave = 64-px row segment.
// Culled (wave,face) pairs contribute < 1.44*2^-16 each.
// ---------------------------------------------------------------------------
__global__ __launch_bounds__(256) void k_partial() {
    const int chunk = blockIdx.x;
    const int row = blockIdx.y;
    const int col = threadIdx.x;
    const float px = col + 0.5f;
    const float py = row + 0.5f;
    const int xlo = col & 192;   // wave-uniform segment start
    const int xhi = xlo + 63;

    const FaceRec* __restrict__ fc = &g_face[chunk * FPC];

    float acc = 0.f;
#pragma unroll 2
    for (int f = 0; f < FPC; ++f) {
        int4 bb = fc[f].bb;
        bool rej = (row < bb.y) | (row > bb.w) | (xhi < bb.x) | (xlo > bb.z);
        if (__all(rej)) continue;          // wave-uniform skip

        float4 a = fc[f].e0;
        float4 b = fc[f].e1;
        float4 c = fc[f].e2;
        float c0 = fmaf(px, a.x, fmaf(py, a.y, a.z));
        float c1 = fmaf(px, b.x, fmaf(py, b.y, b.z));
        float c2 = fmaf(px, c.x, fmaf(py, c.y, c.z));
        float u = fminf(fminf(c0, c1), c2);
        acc += fmaxf(u, 0.f);
        if (__any(fabsf(u) < TCUT)) {      // wave-uniform branch; far lanes add ~0
            acc += __builtin_amdgcn_logf(1.f + __builtin_amdgcn_exp2f(-fabsf(u)));
        }
    }
    g_partial[chunk * (IMG * IMG) + row * IMG + col] = acc;
}

// ---------------------------------------------------------------------------
// Kernel 3: combine chunks, silhouette, squared error, row-mean reduce.
// ---------------------------------------------------------------------------
__global__ __launch_bounds__(256) void k_final(const float* __restrict__ image_ref,
                                               float* __restrict__ out) {
    const int row = blockIdx.x;
    const int col = threadIdx.x;
    const int pix = row * IMG + col;

    float ssum = 0.f;
#pragma unroll
    for (int c = 0; c < NCHUNK; ++c) ssum += g_partial[c * (IMG * IMG) + pix];

    float sil = 1.f - __builtin_amdgcn_exp2f(-ssum);
    float diff = sil - image_ref[pix];
    float v = diff * diff;

#pragma unroll
    for (int o = 32; o > 0; o >>= 1) v += __shfl_down(v, o);

    __shared__ float wsum[4];
    if ((col & 63) == 0) wsum[col >> 6] = v;
    __syncthreads();
    if (col == 0) {
        out[row] = (wsum[0] + wsum[1] + wsum[2] + wsum[3]) * (1.f / 256.f);
    }
}

// ---------------------------------------------------------------------------
extern "C" void kernel_launch(void* const* d_in, const int* in_sizes, int n_in,
                              void* d_out, int out_size, void* d_ws, size_t ws_size,
                              hipStream_t stream) {
    const float* verts = (const float*)d_in[0];      // (1,1000,3) f32
    const int* faces = (const int*)d_in[1];          // (1,1000,3) i32
    const float* q = (const float*)d_in[2];          // (4,) f32
    const float* t = (const float*)d_in[3];          // (3,) f32
    const float* K = (const float*)d_in[4];          // (3,3) f32
    const float* image_ref = (const float*)d_in[5];  // (256,256) f32
    float* out = (float*)d_out;                      // (256,) f32

    k_coeff<<<(NFACE + 255) / 256, 256, 0, stream>>>(verts, faces, q, t, K);
    k_partial<<<dim3(NCHUNK, IMG), 256, 0, stream>>>();
    k_final<<<IMG, 256, 0, stream>>>(image_ref, out);
}